// Round 17
// baseline (566.492 us; speedup 1.0000x reference)
//
#include <hip/hip_runtime.h>

typedef _Float16 f16;
typedef __attribute__((ext_vector_type(8))) _Float16 f16x8;
typedef __attribute__((ext_vector_type(4))) _Float16 f16x4;
typedef __attribute__((ext_vector_type(4))) float f32x4;

#define LOG2E 1.4426950408889634f
#define MFMA16(a, b, c) __builtin_amdgcn_mfma_f32_16x16x32_f16((a), (b), (c), 0, 0, 0)
#define MFMAK16(a, b, c) __builtin_amdgcn_mfma_f32_16x16x16f16((a), (b), (c), 0, 0, 0)

// B=2, N=2048, C=1536, H=8, D=192.  BH=16, tokens=4096.
// d_out layout: out[2,2048,1536] f32 | attn[2,8,2048,2048] f32 | M[192,192] f32
// attn region during pipeline: row r holds MAX-SHIFTED fp16 ps at byte r*8192;
// per-(chunk,kg) scale 2^{m} in mcf[(c*2+kg)][row]; k_tail expands in place.
// MFMA16(X, Y) -> D[lane&15 = Y-row, (lane>>4)*4+r = X-row]

__device__ __forceinline__ void gl16(const void* g, void* l) {
    __builtin_amdgcn_global_load_lds(
        (const __attribute__((address_space(1))) unsigned int*)g,
        (__attribute__((address_space(3))) unsigned int*)l, 16, 0, 0);
}

// ---------------- fp32 -> fp16 converts (merged) ----------------
__global__ void k_cvt_all(const float* __restrict__ x, const float* __restrict__ wq,
                          const float* __restrict__ wp, f16* __restrict__ xh,
                          f16* __restrict__ wqh, f16* __restrict__ wph) {
    int i = blockIdx.x * 256 + threadIdx.x;
    const float4* s; short4* d; int off;
    if (i < 1572864) { s = (const float4*)x; d = (short4*)xh; off = i; }
    else if (i < 3342336) { s = (const float4*)wq; d = (short4*)wqh; off = i - 1572864; }
    else { s = (const float4*)wp; d = (short4*)wph; off = i - 3342336; }
    float4 v = s[off];
    union { f16 h[4]; short4 s4; } u;
    u.h[0] = (f16)v.x; u.h[1] = (f16)v.y; u.h[2] = (f16)v.z; u.h[3] = (f16)v.w;
    d[off] = u.s4;
}

// Mt[d][e] = M[e][d]
__global__ void k_cvtM(const float* __restrict__ M, f16* __restrict__ Mt) {
    int i = blockIdx.x * 256 + threadIdx.x;
    if (i >= 192 * 192) return;
    int d = i / 192, e = i - (i / 192) * 192;
    Mt[d * 192 + e] = (f16)M[e * 192 + d];
}

// ---------------- QKV projection GEMM ----------------
__global__ __launch_bounds__(256) void k_gemm_qkv(
    const f16* __restrict__ A, const f16* __restrict__ Bw,
    f16* __restrict__ Qh, f16* __restrict__ Kh, f16* __restrict__ Vp)
{
    __shared__ __align__(16) char S[32768];
    const int tid = threadIdx.x, lane = tid & 63, w = tid >> 6;
    const int bid = blockIdx.x;
    const int xcd = bid & 7, cc = bid >> 3;
    const int mb = xcd * 4 + cc / 36, nb = cc - (cc / 36) * 36;
    const int m0 = mb * 128, n0 = nb * 128;
    const int sec = nb >= 24 ? 2 : (nb >= 12 ? 1 : 0);
    const int wm = (w & 1) * 64, wn = (w >> 1) * 64;
    const int L = lane & 15, g = lane >> 4;
    const char* Ab = (const char*)A;
    const char* Bb = (const char*)Bw;

    const char* gA[2]; const char* gB[2]; int ldso[2];
#pragma unroll
    for (int q = 0; q < 2; ++q) {
        int s = w * 128 + q * 64 + lane;
        int swz = ((s & 3) ^ ((s >> 2) & 3)) * 16;
        gA[q] = Ab + (size_t)(m0 + (s >> 2)) * 3072 + swz;
        gB[q] = Bb + (size_t)(n0 + (s >> 2)) * 3072 + swz;
        ldso[q] = w * 2048 + q * 1024;
    }
    const int gx = ((g ^ (L & 3)) << 4);

    f32x4 acc[4][4] = {};
#pragma unroll
    for (int q = 0; q < 2; ++q) {
        gl16(gA[q], S + ldso[q]);
        gl16(gB[q], S + 8192 + ldso[q]);
    }
    int buf = 0;
    for (int kk = 0; kk < 48; ++kk) {
        __syncthreads();
        if (kk < 47) {
            int nb_ = (buf ^ 1) * 16384;
#pragma unroll
            for (int q = 0; q < 2; ++q) {
                gl16(gA[q] + (kk + 1) * 64, S + nb_ + ldso[q]);
                gl16(gB[q] + (kk + 1) * 64, S + nb_ + 8192 + ldso[q]);
            }
        }
        const char* AsB = S + buf * 16384;
        const char* BsB = AsB + 8192;
        f16x8 af[4], bf[4];
#pragma unroll
        for (int i = 0; i < 4; ++i) {
            af[i] = *(const f16x8*)(AsB + (wm + i * 16 + L) * 64 + gx);
            bf[i] = *(const f16x8*)(BsB + (wn + i * 16 + L) * 64 + gx);
        }
        if (sec < 2) {
#pragma unroll
            for (int i = 0; i < 4; ++i)
#pragma unroll
                for (int j = 0; j < 4; ++j)
                    acc[i][j] = MFMA16(bf[j], af[i], acc[i][j]);
        } else {
#pragma unroll
            for (int i = 0; i < 4; ++i)
#pragma unroll
                for (int j = 0; j < 4; ++j)
                    acc[i][j] = MFMA16(af[i], bf[j], acc[i][j]);
        }
        buf ^= 1;
    }

    if (sec == 2) {
#pragma unroll
        for (int i = 0; i < 4; ++i)
#pragma unroll
            for (int j = 0; j < 4; ++j) {
                int rem = n0 + wn + j * 16 + L - 3072;
                int h = rem / 192, d = rem - h * 192;
                int gm = m0 + wm + i * 16 + g * 4;
                int gb = gm >> 11, nn = gm & 2047;
                union { f16 h4[4]; short4 s4; } u;
#pragma unroll
                for (int r = 0; r < 4; ++r) u.h4[r] = (f16)acc[i][j][r];
                *(short4*)(Vp + (size_t)((gb * 8 + h) * 192 + d) * 2048 + nn) = u.s4;  // UNPERMUTED
            }
    } else {
        f16* base = sec == 0 ? Qh : Kh;
#pragma unroll
        for (int i = 0; i < 4; ++i) {
            int gm = m0 + wm + i * 16 + L;
            int gb = gm >> 11, nn = gm & 2047;
#pragma unroll
            for (int j = 0; j < 4; ++j) {
                int rem = n0 + wn + j * 16 + g * 4 - sec * 1536;
                int h = rem / 192, d = rem - h * 192;
                union { f16 h4[4]; short4 s4; } u;
#pragma unroll
                for (int r = 0; r < 4; ++r) u.h4[r] = (f16)acc[i][j][r];
                *(short4*)(base + (size_t)((gb * 8 + h) * 2048 + nn) * 192 + d) = u.s4;
            }
        }
    }
}

// ---------------- apply metric M + kMk row form ----------------
__global__ __launch_bounds__(256) void k_mgemm(
    const f16* __restrict__ Qh, const f16* __restrict__ Kh,
    const f16* __restrict__ Mt, f16* __restrict__ QMh,
    const float* __restrict__ scale_p, float* __restrict__ kmk)
{
    const int tid = threadIdx.x, lane = tid & 63, w = tid >> 6;
    const int L = lane & 15, g = lane >> 4;
    const int isK = blockIdx.y;
    const f16* src = isK ? Kh : Qh;
    const int row0 = blockIdx.x * 64 + w * 16;
    const int tokrow = row0 + L;
    f16x8 af[6];
#pragma unroll
    for (int ks = 0; ks < 6; ++ks)
        af[ks] = *(const f16x8*)((const char*)src + (size_t)tokrow * 384 + ks * 64 + g * 16);
    f32x4 acc[12] = {};
#pragma unroll
    for (int ct = 0; ct < 12; ++ct)
#pragma unroll
        for (int ks = 0; ks < 6; ++ks) {
            f16x8 bf = *(const f16x8*)((const char*)Mt + (ct * 16 + L) * 384 + ks * 64 + g * 16);
            acc[ct] = MFMA16(bf, af[ks], acc[ct]);
        }
    if (!isK) {
#pragma unroll
        for (int ct = 0; ct < 12; ++ct) {
            union { f16 h4[4]; short4 s4; } u;
#pragma unroll
            for (int r = 0; r < 4; ++r) u.h4[r] = (f16)acc[ct][r];
            *(short4*)(QMh + (size_t)tokrow * 192 + ct * 16 + g * 4) = u.s4;
        }
        return;
    }
    float s = 0.f;
#pragma unroll
    for (int ct = 0; ct < 12; ++ct) {
        union { short4 s4; f16 h[4]; } kv;
        kv.s4 = *(const short4*)(src + (size_t)tokrow * 192 + ct * 16 + g * 4);
#pragma unroll
        for (int r = 0; r < 4; ++r) s += acc[ct][r] * (float)kv.h[r];
    }
    s += __shfl_xor(s, 16); s += __shfl_xor(s, 32);
    if (lane < 16) kmk[row0 + lane] = s * scale_p[0] * LOG2E;
}

// ---------------- attention: kg-split, 3 blocks/CU ----------------
// grid 1024: bh=(bx&7)*2+(bx>>9), qb=(bx>>3)&63 -> 32 rows. waves: qg=w&1 (16-row
// tile), kg=w>>1 (16-col half of each 32-chunk). Crow dropped (cancels).
// LDS single array: K dbuf 2x12288 | V dbuf 2x13824 (72B rows) = 52224 bytes.
__global__ __launch_bounds__(256) void k_attn(
    const f16* __restrict__ QMh, const f16* __restrict__ Kh,
    const f16* __restrict__ Vp, const float* __restrict__ kmk,
    const float* __restrict__ scale_p,
    char* __restrict__ attnB, f16* __restrict__ ctx,
    float* __restrict__ lrow, float* __restrict__ mcf)
{
    __shared__ __align__(16) char SH[52224];
    const int tid = threadIdx.x, lane = tid & 63, w = tid >> 6;
    const int L = lane & 15, g = lane >> 4;
    const int qg = w & 1, kg = w >> 1;
    const int bx = blockIdx.x;
    const int bh = (bx & 7) * 2 + (bx >> 9);
    const int qb = (bx >> 3) & 63;
    const int rowt = qb * 32 + qg * 16;
    const int rowi = bh * 2048 + rowt + L;
    const float a2 = 2.f * scale_p[0] * LOG2E;

    const char* qbase = (const char*)QMh + (size_t)(bh * 2048 + rowt) * 384;
    f16x8 qf[6];
#pragma unroll
    for (int ks = 0; ks < 6; ++ks)
        qf[ks] = *(const f16x8*)(qbase + L * 384 + ks * 64 + g * 16);
    const char* Kb = (const char*)Kh + (size_t)bh * 2048 * 384;
    const char* Vb = (const char*)Vp + (size_t)bh * 192 * 4096;
    const float* kmkrow = kmk + bh * 2048;

    int ksrc[3], kdst[3], vsrc[3], vdst[3];
#pragma unroll
    for (int i = 0; i < 3; ++i) {
        int s = tid + 256 * i;
        int r = s / 24, c16 = s - r * 24;
        ksrc[i] = r * 384 + c16 * 16;
        kdst[i] = r * 384 + (((c16 & ~7) | ((c16 & 7) ^ (r & 7))) << 4);
        vsrc[i] = (s >> 2) * 4096 + (s & 3) * 16;
        vdst[i] = (s >> 2) * 72 + (s & 3) * 16;
    }
    int kslot[6];
#pragma unroll
    for (int ks = 0; ks < 6; ++ks) {
        int slot = ks * 4 + g;
        kslot[ks] = (((slot & ~7) | ((slot & 7) ^ (L & 7))) << 4);
    }
    const int krow = (kg * 16 + L) * 384;

    int4 stk[3], stv[3];
#pragma unroll
    for (int i = 0; i < 3; ++i) {
        stk[i] = *(const int4*)(Kb + ksrc[i]);
        stv[i] = *(const int4*)(Vb + vsrc[i]);
    }
    f32x4 cacc[12] = {};
    float lacc = 0.f, m_run = -3.0e38f;
    char* arow16 = attnB + (size_t)rowi * 8192;

    for (int c = 0; c < 64; ++c) {
        char* Kl = SH + (c & 1) * 12288;
        char* Vl = SH + 24576 + (c & 1) * 13824;
#pragma unroll
        for (int i = 0; i < 3; ++i) {
            *(int4*)(Kl + kdst[i]) = stk[i];
            *(int2*)(Vl + vdst[i])     = make_int2(stv[i].x, stv[i].y);
            *(int2*)(Vl + vdst[i] + 8) = make_int2(stv[i].z, stv[i].w);
        }
        if (c < 63) {
#pragma unroll
            for (int i = 0; i < 3; ++i) {
                stk[i] = *(const int4*)(Kb + (size_t)(c + 1) * 12288 + ksrc[i]);
                stv[i] = *(const int4*)(Vb + (size_t)(c + 1) * 64 + vsrc[i]);
            }
        }
        __syncthreads();
        f32x4 a0 = {};
        __builtin_amdgcn_s_setprio(1);
#pragma unroll
        for (int ks = 0; ks < 6; ++ks) {
            f16x8 kf = *(const f16x8*)(Kl + krow + kslot[ks]);
            a0 = MFMA16(kf, qf[ks], a0);
        }
        __builtin_amdgcn_s_setprio(0);
        float4 km = *(const float4*)(kmkrow + c * 32 + kg * 16 + g * 4);
        float e4[4];
        e4[0] = a2 * a0[0] - km.x;
        e4[1] = a2 * a0[1] - km.y;
        e4[2] = a2 * a0[2] - km.z;
        e4[3] = a2 * a0[3] - km.w;
        float mx = fmaxf(fmaxf(e4[0], e4[1]), fmaxf(e4[2], e4[3]));
        mx = fmaxf(mx, __shfl_xor(mx, 16));
        mx = fmaxf(mx, __shfl_xor(mx, 32));
        if (__any(mx > m_run + 4.f)) {
            float mnew = fmaxf(m_run, mx);
            float fr = __builtin_amdgcn_exp2f(m_run - mnew);
            lacc *= fr;
            float frc[4];
#pragma unroll
            for (int r = 0; r < 4; ++r) frc[r] = __shfl(fr, g * 4 + r);
#pragma unroll
            for (int dt = 0; dt < 12; ++dt)
#pragma unroll
                for (int r = 0; r < 4; ++r) cacc[dt][r] *= frc[r];
            m_run = mnew;
        }
        if (g == 0) mcf[(size_t)(c * 2 + kg) * 32768 + rowi] = __builtin_amdgcn_exp2f(m_run);
        float ps[4];
#pragma unroll
        for (int j = 0; j < 4; ++j)
            ps[j] = __builtin_amdgcn_exp2f(e4[j] - m_run);
        lacc += (ps[0] + ps[1]) + (ps[2] + ps[3]);
        union { f16x4 v; int2 i2; } pa;
        pa.v[0] = (f16)ps[0]; pa.v[1] = (f16)ps[1]; pa.v[2] = (f16)ps[2]; pa.v[3] = (f16)ps[3];
        *(int2*)(arow16 + c * 64 + kg * 32 + g * 8) = pa.i2;
        __builtin_amdgcn_s_setprio(1);
#pragma unroll
        for (int dt = 0; dt < 12; ++dt) {
            f16x4 vf = *(const f16x4*)(Vl + (dt * 16 + L) * 72 + kg * 32 + g * 8);
            cacc[dt] = MFMAK16(pa.v, vf, cacc[dt]);
        }
        __builtin_amdgcn_s_setprio(0);
    }
    // reduce l over g replicas (per row L, per kg)
    lacc += __shfl_xor(lacc, 16);
    lacc += __shfl_xor(lacc, 32);

    // ---- combine kg halves: m, l, cacc ----
    __syncthreads();
    float* hdr = (float*)(SH + 24576);            // [qg][32]: m(16) l(16)
    float* cb  = (float*)SH;                      // 2 waves x 64 lanes x 48 f32 = 24576B
    if (kg == 1) {
        if (g == 0) { hdr[qg * 32 + L] = m_run; hdr[qg * 32 + 16 + L] = lacc; }
        float* my = cb + (qg * 64 + lane) * 48;
#pragma unroll
        for (int dt = 0; dt < 12; ++dt) *(f32x4*)(my + dt * 4) = cacc[dt];
    }
    __syncthreads();
    if (kg == 0) {
        float m1 = hdr[qg * 32 + L], l1 = hdr[qg * 32 + 16 + L];
        float mt = fmaxf(m_run, m1);
        float w0 = __builtin_amdgcn_exp2f(m_run - mt);
        float w1 = __builtin_amdgcn_exp2f(m1 - mt);
        float lt = lacc * w0 + l1 * w1;
        if (g == 0) lrow[rowi] = __builtin_amdgcn_exp2f(-mt) / lt;
        float f0 = w0 / lt, f1 = w1 / lt;
        float f0r[4], f1r[4];
#pragma unroll
        for (int r = 0; r < 4; ++r) {
            f0r[r] = __shfl(f0, g * 4 + r);
            f1r[r] = __shfl(f1, g * 4 + r);
        }
        const float* other = cb + (qg * 64 + lane) * 48;
        char* scr = SH + 24576 + 2048 + qg * 6144;   // [16 tok][384B], above hdr
#pragma unroll
        for (int dt = 0; dt < 12; ++dt)
#pragma unroll
            for (int r = 0; r < 4; ++r)
                *(f16*)(scr + (g * 4 + r) * 384 + (dt * 16 + L) * 2)
                    = (f16)(cacc[dt][r] * f0r[r] + other[dt * 4 + r] * f1r[r]);
        const int b = bh >> 3, h = bh & 7;
#pragma unroll
        for (int t = 0; t < 6; ++t) {
            int chunk = t * 64 + lane;
            int tok = chunk / 24, c16 = chunk - tok * 24;
            int4 v = *(const int4*)(scr + tok * 384 + c16 * 16);
            *(int4*)((char*)ctx + ((size_t)(b * 2048 + rowt + tok) * 1536 + h * 192) * 2 + c16 * 16) = v;
        }
    }
}

// ---------------- fused tail: proj GEMM (0..383) || fp16->fp32 normalize ----------------
__global__ __launch_bounds__(256) void k_tail(
    const f16* __restrict__ A, const f16* __restrict__ Bw,
    const float* __restrict__ bias, float* __restrict__ out,
    char* __restrict__ attnB, const float* __restrict__ lrow,
    const float* __restrict__ mcf)
{
    const int tid = threadIdx.x;
    if (blockIdx.x >= 384) {
        const int row = (blockIdx.x - 384) * 8 + (tid >> 5);
        const int t = tid & 31;
        const float lr = lrow[row];
        char* slot = attnB + (size_t)row * 8192;
        short4 s4[16];
        float fc[16];
#pragma unroll
        for (int i = 0; i < 16; ++i) {
            s4[i] = *(const short4*)(slot + t * 8 + i * 256);   // cols t*4 + i*128
            int chunk = i * 4 + (t >> 3), kg = (t >> 2) & 1;
            fc[i] = mcf[(size_t)(chunk * 2 + kg) * 32768 + row] * lr;
        }
        asm volatile("s_waitcnt vmcnt(0)" ::: "memory");
#pragma unroll
        for (int i = 0; i < 16; ++i) {
            union { short4 v; f16 h[4]; } u; u.v = s4[i];
            f32x4 o = { (float)u.h[0] * fc[i], (float)u.h[1] * fc[i],
                        (float)u.h[2] * fc[i], (float)u.h[3] * fc[i] };
            __builtin_nontemporal_store(o, (f32x4*)(slot + t * 16 + i * 512));
        }
        return;
    }
    __shared__ __align__(16) char S[32768];
    const int lane = tid & 63, w = tid >> 6;
    const int bid = blockIdx.x;
    const int xcd = bid & 7, cc = bid >> 3;
    const int mb = xcd * 4 + cc / 12, nbk = cc - (cc / 12) * 12;
    const int m0 = mb * 128, n0 = nbk * 128;
    const int wm = (w & 1) * 64, wn = (w >> 1) * 64;
    const int L = lane & 15, g = lane >> 4;
    const char* Ab = (const char*)A;
    const char* Bb = (const char*)Bw;

    const char* gA[2]; const char* gB[2]; int ldso[2];
#pragma unroll
    for (int q = 0; q < 2; ++q) {
        int s = w * 128 + q * 64 + lane;
        int swz = ((s & 3) ^ ((s >> 2) & 3)) * 16;
        gA[q] = Ab + (size_t)(m0 + (s >> 2)) * 3072 + swz;
        gB[q] = Bb + (size_t)(n0 + (s >> 2)) * 3072 + swz;
        ldso[q] = w * 2048 + q * 1024;
    }
    const int gx = ((g ^ (L & 3)) << 4);

    f32x4 acc[4][4] = {};
#pragma unroll
    for (int q = 0; q < 2; ++q) {
        gl16(gA[q], S + ldso[q]);
        gl16(gB[q], S + 8192 + ldso[q]);
    }
    int buf = 0;
    for (int kk = 0; kk < 48; ++kk) {
        __syncthreads();
        if (kk < 47) {
            int nb_ = (buf ^ 1) * 16384;
#pragma unroll
            for (int q = 0; q < 2; ++q) {
                gl16(gA[q] + (kk + 1) * 64, S + nb_ + ldso[q]);
                gl16(gB[q] + (kk + 1) * 64, S + nb_ + 8192 + ldso[q]);
            }
        }
        const char* AsB = S + buf * 16384;
        const char* BsB = AsB + 8192;
        f16x8 af[4], bf[4];
#pragma unroll
        for (int i = 0; i < 4; ++i) {
            af[i] = *(const f16x8*)(AsB + (wm + i * 16 + L) * 64 + gx);
            bf[i] = *(const f16x8*)(BsB + (wn + i * 16 + L) * 64 + gx);
        }
#pragma unroll
        for (int i = 0; i < 4; ++i)
#pragma unroll
            for (int j = 0; j < 4; ++j)
                acc[i][j] = MFMA16(bf[j], af[i], acc[i][j]);
        buf ^= 1;
    }
#pragma unroll
    for (int i = 0; i < 4; ++i) {
        int token = m0 + wm + i * 16 + L;
#pragma unroll
        for (int j = 0; j < 4; ++j) {
            int gnb = n0 + wn + j * 16 + g * 4;
            float4 bv = *(const float4*)(bias + gnb);
            float4 v = make_float4(acc[i][j][0] + bv.x, acc[i][j][1] + bv.y,
                                   acc[i][j][2] + bv.z, acc[i][j][3] + bv.w);
            *(float4*)(out + (size_t)token * 1536 + gnb) = v;
        }
    }
}

extern "C" void kernel_launch(void* const* d_in, const int* in_sizes, int n_in,
                              void* d_out, int out_size, void* d_ws, size_t ws_size,
                              hipStream_t stream)
{
    const float* x     = (const float*)d_in[0];
    const float* Wqkv  = (const float*)d_in[1];
    const float* Wproj = (const float*)d_in[2];
    const float* bproj = (const float*)d_in[3];
    const float* scale = (const float*)d_in[4];
    const float* M     = (const float*)d_in[5];
    float* out  = (float*)d_out;
    char* attnB = (char*)(out + 6291456);

    char* p = (char*)d_ws;
    f16* x_h     = (f16*)p;  p += 12582912;
    f16* Wqkv_h  = (f16*)p;  p += 14155776;
    f16* Wproj_h = (f16*)p;  p += 4718592;
    f16* Mt_h    = (f16*)p;  p += 73728;
    f16* Qh      = (f16*)p;  p += 12582912;
    f16* Kh      = (f16*)p;  p += 12582912;
    f16* Vp      = (f16*)p;  p += 12582912;
    f16* QMh     = (f16*)p;  p += 12582912;
    float* kmk   = (float*)p; p += 131072;
    float* lrow  = (float*)p; p += 131072;
    float* mcf   = (float*)p; p += 16777216;
    f16* ctx     = (f16*)p;  p += 12582912;

    k_cvt_all<<<15360, 256, 0, stream>>>(x, Wqkv, Wproj, x_h, Wqkv_h, Wproj_h);
    k_cvtM<<<144, 256, 0, stream>>>(M, Mt_h);
    k_gemm_qkv<<<1152, 256, 0, stream>>>(x_h, Wqkv_h, Qh, Kh, Vp);
    k_mgemm<<<dim3(512, 2), 256, 0, stream>>>(Qh, Kh, Mt_h, QMh, scale, kmk);
    k_attn<<<1024, 256, 0, stream>>>(QMh, Kh, Vp, kmk, scale, attnB, ctx, lrow, mcf);
    k_tail<<<4480, 256, 0, stream>>>(ctx, Wproj_h, bproj, out, attnB, lrow, mcf);
    hipMemcpyAsync(out + 73400320, M, 36864 * 4, hipMemcpyDeviceToDevice, stream);
}

// Round 18
// 386.734 us; speedup vs baseline: 1.4648x; 1.4648x over previous
//
#include <hip/hip_runtime.h>

typedef _Float16 f16;
typedef __attribute__((ext_vector_type(8))) _Float16 f16x8;
typedef __attribute__((ext_vector_type(4))) float f32x4;

#define LOG2E 1.4426950408889634f
#define MFMA16(a, b, c) __builtin_amdgcn_mfma_f32_16x16x32_f16((a), (b), (c), 0, 0, 0)

// B=2, N=2048, C=1536, H=8, D=192.  BH=16, tokens=4096.
// d_out layout: out[2,2048,1536] f32 | attn[2,8,2048,2048] f32 | M[192,192] f32
// attn region during pipeline: row r holds MAX-SHIFTED fp16 ps = exp2(e - m_c)
// at byte r*8192. Per-chunk scale 2^{m_c} in mcf[c][row]; k_tail expands
// in place: attn = ps * mcf * lrow.
// MFMA16(X, Y) -> D[lane&15 = Y-row, (lane>>4)*4+r = X-row]

__device__ __forceinline__ void gl16(const void* g, void* l) {
    __builtin_amdgcn_global_load_lds(
        (const __attribute__((address_space(1))) unsigned int*)g,
        (__attribute__((address_space(3))) unsigned int*)l, 16, 0, 0);
}

// ---------------- fp32 -> fp16 converts (merged, incl. M transpose) ----------------
__global__ void k_cvt_all(const float* __restrict__ x, const float* __restrict__ wq,
                          const float* __restrict__ wp, const float* __restrict__ M,
                          f16* __restrict__ xh, f16* __restrict__ wqh,
                          f16* __restrict__ wph, f16* __restrict__ Mt) {
    int i = blockIdx.x * 256 + threadIdx.x;
    if (i >= 3932160) {                      // Mt[d][e] = M[e][d], 36864 elems
        int j = i - 3932160;
        int d = j / 192, e = j - d * 192;
        Mt[d * 192 + e] = (f16)M[e * 192 + d];
        return;
    }
    const float4* s; short4* d; int off;
    if (i < 1572864) { s = (const float4*)x; d = (short4*)xh; off = i; }
    else if (i < 3342336) { s = (const float4*)wq; d = (short4*)wqh; off = i - 1572864; }
    else { s = (const float4*)wp; d = (short4*)wph; off = i - 3342336; }
    float4 v = s[off];
    union { f16 h[4]; short4 s4; } u;
    u.h[0] = (f16)v.x; u.h[1] = (f16)v.y; u.h[2] = (f16)v.z; u.h[3] = (f16)v.w;
    d[off] = u.s4;
}

// ---------------- QKV projection GEMM (async global_load_lds, dbuf, 1 barrier/iter) ----------------
__global__ __launch_bounds__(256) void k_gemm_qkv(
    const f16* __restrict__ A, const f16* __restrict__ Bw,
    f16* __restrict__ Qh, f16* __restrict__ Kh, f16* __restrict__ Vp)
{
    __shared__ __align__(16) char S[32768];
    const int tid = threadIdx.x, lane = tid & 63, w = tid >> 6;
    const int bid = blockIdx.x;
    const int xcd = bid & 7, cc = bid >> 3;
    const int mb = xcd * 4 + cc / 36, nb = cc - (cc / 36) * 36;
    const int m0 = mb * 128, n0 = nb * 128;
    const int sec = nb >= 24 ? 2 : (nb >= 12 ? 1 : 0);
    const int wm = (w & 1) * 64, wn = (w >> 1) * 64;
    const int L = lane & 15, g = lane >> 4;
    const char* Ab = (const char*)A;
    const char* Bb = (const char*)Bw;

    const char* gA[2]; const char* gB[2]; int ldso[2];
#pragma unroll
    for (int q = 0; q < 2; ++q) {
        int s = w * 128 + q * 64 + lane;
        int swz = ((s & 3) ^ ((s >> 2) & 3)) * 16;
        gA[q] = Ab + (size_t)(m0 + (s >> 2)) * 3072 + swz;
        gB[q] = Bb + (size_t)(n0 + (s >> 2)) * 3072 + swz;
        ldso[q] = w * 2048 + q * 1024;
    }
    const int gx = ((g ^ (L & 3)) << 4);

    f32x4 acc[4][4] = {};
#pragma unroll
    for (int q = 0; q < 2; ++q) {
        gl16(gA[q], S + ldso[q]);
        gl16(gB[q], S + 8192 + ldso[q]);
    }
    int buf = 0;
    for (int kk = 0; kk < 48; ++kk) {
        __syncthreads();
        if (kk < 47) {
            int nb_ = (buf ^ 1) * 16384;
#pragma unroll
            for (int q = 0; q < 2; ++q) {
                gl16(gA[q] + (kk + 1) * 64, S + nb_ + ldso[q]);
                gl16(gB[q] + (kk + 1) * 64, S + nb_ + 8192 + ldso[q]);
            }
        }
        const char* AsB = S + buf * 16384;
        const char* BsB = AsB + 8192;
        f16x8 af[4], bf[4];
#pragma unroll
        for (int i = 0; i < 4; ++i) {
            af[i] = *(const f16x8*)(AsB + (wm + i * 16 + L) * 64 + gx);
            bf[i] = *(const f16x8*)(BsB + (wn + i * 16 + L) * 64 + gx);
        }
        if (sec < 2) {
#pragma unroll
            for (int i = 0; i < 4; ++i)
#pragma unroll
                for (int j = 0; j < 4; ++j)
                    acc[i][j] = MFMA16(bf[j], af[i], acc[i][j]);
        } else {
#pragma unroll
            for (int i = 0; i < 4; ++i)
#pragma unroll
                for (int j = 0; j < 4; ++j)
                    acc[i][j] = MFMA16(af[i], bf[j], acc[i][j]);
        }
        buf ^= 1;
    }

    if (sec == 2) {
#pragma unroll
        for (int i = 0; i < 4; ++i)
#pragma unroll
            for (int j = 0; j < 4; ++j) {
                int rem = n0 + wn + j * 16 + L - 3072;
                int h = rem / 192, d = rem - h * 192;
                int gm = m0 + wm + i * 16 + g * 4;
                int gb = gm >> 11, nn = gm & 2047;
                union { f16 h4[4]; short4 s4; } u;
#pragma unroll
                for (int r = 0; r < 4; ++r) u.h4[r] = (f16)acc[i][j][r];
                int nnp = (nn & ~31) | (((nn >> 2) & 3) << 3) | (((nn >> 4) & 1) << 2) | (nn & 3);
                *(short4*)(Vp + (size_t)((gb * 8 + h) * 192 + d) * 2048 + nnp) = u.s4;
            }
    } else {
        f16* base = sec == 0 ? Qh : Kh;
#pragma unroll
        for (int i = 0; i < 4; ++i) {
            int gm = m0 + wm + i * 16 + L;
            int gb = gm >> 11, nn = gm & 2047;
#pragma unroll
            for (int j = 0; j < 4; ++j) {
                int rem = n0 + wn + j * 16 + g * 4 - sec * 1536;
                int h = rem / 192, d = rem - h * 192;
                union { f16 h4[4]; short4 s4; } u;
#pragma unroll
                for (int r = 0; r < 4; ++r) u.h4[r] = (f16)acc[i][j][r];
                *(short4*)(base + (size_t)((gb * 8 + h) * 2048 + nn) * 192 + d) = u.s4;
            }
        }
    }
}

// ---------------- apply metric M + row quadratic forms ----------------
__global__ __launch_bounds__(256) void k_mgemm(
    const f16* __restrict__ Qh, const f16* __restrict__ Kh,
    const f16* __restrict__ Mt, f16* __restrict__ QMh,
    const float* __restrict__ scale_p, float* __restrict__ qmq, float* __restrict__ kmk)
{
    const int tid = threadIdx.x, lane = tid & 63, w = tid >> 6;
    const int L = lane & 15, g = lane >> 4;
    const int isK = blockIdx.y;
    const f16* src = isK ? Kh : Qh;
    float* rowdot = isK ? kmk : qmq;
    const int row0 = blockIdx.x * 64 + w * 16;
    const int tokrow = row0 + L;
    f16x8 af[6];
#pragma unroll
    for (int ks = 0; ks < 6; ++ks)
        af[ks] = *(const f16x8*)((const char*)src + (size_t)tokrow * 384 + ks * 64 + g * 16);
    f32x4 acc[12] = {};
#pragma unroll
    for (int ct = 0; ct < 12; ++ct)
#pragma unroll
        for (int ks = 0; ks < 6; ++ks) {
            f16x8 bf = *(const f16x8*)((const char*)Mt + (ct * 16 + L) * 384 + ks * 64 + g * 16);
            acc[ct] = MFMA16(bf, af[ks], acc[ct]);
        }
    if (!isK) {
#pragma unroll
        for (int ct = 0; ct < 12; ++ct) {
            union { f16 h4[4]; short4 s4; } u;
#pragma unroll
            for (int r = 0; r < 4; ++r) u.h4[r] = (f16)acc[ct][r];
            *(short4*)(QMh + (size_t)tokrow * 192 + ct * 16 + g * 4) = u.s4;
        }
    }
    float s = 0.f;
#pragma unroll
    for (int ct = 0; ct < 12; ++ct) {
        union { short4 s4; f16 h[4]; } kv;
        kv.s4 = *(const short4*)(src + (size_t)tokrow * 192 + ct * 16 + g * 4);
#pragma unroll
        for (int r = 0; r < 4; ++r) s += acc[ct][r] * (float)kv.h[r];
    }
    s += __shfl_xor(s, 16); s += __shfl_xor(s, 32);
    if (lane < 16) rowdot[row0 + lane] = s * scale_p[0] * LOG2E;
}

// ---------------- single-pass attention: shifted fp16 ps + per-chunk scale ----------------
__global__ __launch_bounds__(256) void k_attn(
    const f16* __restrict__ QMh, const f16* __restrict__ Kh,
    const f16* __restrict__ Vp, const float* __restrict__ kmk,
    const float* __restrict__ qmq, const float* __restrict__ scale_p,
    char* __restrict__ attnB, f16* __restrict__ ctx,
    float* __restrict__ lrow, float* __restrict__ mcf)
{
    __shared__ __align__(16) char KsB[2][12288];   // reused as ctx scratch at end
    __shared__ __align__(16) char VsB[2][15360];
    const int tid = threadIdx.x, lane = tid & 63, w = tid >> 6;
    const int L = lane & 15, g = lane >> 4;
    const int bx = blockIdx.x;
    const int bh = (bx & 7) * 2 + (bx >> 8);
    const int qb = (bx >> 3) & 31;
    const int row0 = qb * 64 + w * 16;
    const float a2 = 2.f * scale_p[0] * LOG2E;

    const char* qbase = (const char*)QMh + (size_t)(bh * 2048 + row0) * 384;
    f16x8 qf[6];
#pragma unroll
    for (int ks = 0; ks < 6; ++ks)
        qf[ks] = *(const f16x8*)(qbase + L * 384 + ks * 64 + g * 16);
    const char* Kb = (const char*)Kh + (size_t)bh * 2048 * 384;
    const char* Vb = (const char*)Vp + (size_t)bh * 192 * 4096;
    const float* kmkrow = kmk + bh * 2048;
    const int rowi = bh * 2048 + row0 + L;
    const float Crow = qmq[rowi];

    int ksrc[3], kdst[3], vsrc[3], vdst[3];
#pragma unroll
    for (int i = 0; i < 3; ++i) {
        int s = tid + 256 * i;
        int r = s / 24, c16 = s - r * 24;
        ksrc[i] = r * 384 + c16 * 16;
        kdst[i] = r * 384 + (((c16 & ~7) | ((c16 & 7) ^ (r & 7))) << 4);
        vsrc[i] = (s >> 2) * 4096 + (s & 3) * 16;
        vdst[i] = (s >> 2) * 80 + (s & 3) * 16;
    }
    int kslot[6];
#pragma unroll
    for (int ks = 0; ks < 6; ++ks) {
        int slot = ks * 4 + g;
        kslot[ks] = (((slot & ~7) | ((slot & 7) ^ (L & 7))) << 4);
    }

    int4 stk[3], stv[3];
#pragma unroll
    for (int i = 0; i < 3; ++i) {
        stk[i] = *(const int4*)(Kb + ksrc[i]);
        stv[i] = *(const int4*)(Vb + vsrc[i]);
    }
    f32x4 cacc[12] = {};
    float lacc = 0.f;
    float m_run = -3.0e38f, scinv = 0.f;
    char* arow16 = attnB + (size_t)rowi * 8192;   // fp16 row slot

    for (int c = 0; c < 64; ++c) {
        char* Kl = KsB[c & 1];
        char* Vl = VsB[c & 1];
#pragma unroll
        for (int i = 0; i < 3; ++i) {
            *(int4*)(Kl + kdst[i]) = stk[i];
            *(int4*)(Vl + vdst[i]) = stv[i];
        }
        if (c < 63) {
#pragma unroll
            for (int i = 0; i < 3; ++i) {
                stk[i] = *(const int4*)(Kb + (size_t)(c + 1) * 12288 + ksrc[i]);
                stv[i] = *(const int4*)(Vb + (size_t)(c + 1) * 64 + vsrc[i]);
            }
        }
        __syncthreads();
        f32x4 a0 = {}, a1 = {};
        __builtin_amdgcn_s_setprio(1);
#pragma unroll
        for (int ks = 0; ks < 6; ++ks) {
            f16x8 kf0 = *(const f16x8*)(Kl + L * 384 + kslot[ks]);
            f16x8 kf1 = *(const f16x8*)(Kl + (16 + L) * 384 + kslot[ks]);
            a0 = MFMA16(kf0, qf[ks], a0);
            a1 = MFMA16(kf1, qf[ks], a1);
        }
        __builtin_amdgcn_s_setprio(0);
        float4 km0 = *(const float4*)(kmkrow + c * 32 + g * 4);
        float4 km1 = *(const float4*)(kmkrow + c * 32 + 16 + g * 4);
        float e8[8];
        e8[0] = a2 * a0[0] - km0.x - Crow;
        e8[1] = a2 * a0[1] - km0.y - Crow;
        e8[2] = a2 * a0[2] - km0.z - Crow;
        e8[3] = a2 * a0[3] - km0.w - Crow;
        e8[4] = a2 * a1[0] - km1.x - Crow;
        e8[5] = a2 * a1[1] - km1.y - Crow;
        e8[6] = a2 * a1[2] - km1.z - Crow;
        e8[7] = a2 * a1[3] - km1.w - Crow;
        float mx = fmaxf(fmaxf(fmaxf(e8[0], e8[1]), fmaxf(e8[2], e8[3])),
                         fmaxf(fmaxf(e8[4], e8[5]), fmaxf(e8[6], e8[7])));
        mx = fmaxf(mx, __shfl_xor(mx, 16));
        mx = fmaxf(mx, __shfl_xor(mx, 32));
        if (__any(mx > m_run + 4.f)) {    // first chunk ALWAYS triggers -> m_run finite below
            float mnew = fmaxf(m_run, mx);
            float fr = __builtin_amdgcn_exp2f(m_run - mnew);
            lacc *= fr;
            float frc[4];
#pragma unroll
            for (int r = 0; r < 4; ++r) frc[r] = __shfl(fr, g * 4 + r);
#pragma unroll
            for (int dt = 0; dt < 12; ++dt)
#pragma unroll
                for (int r = 0; r < 4; ++r) cacc[dt][r] *= frc[r];
            m_run = mnew;
            scinv = __builtin_amdgcn_exp2f(m_run);
        }
        if (g == 0) mcf[(size_t)c * 32768 + rowi] = scinv;   // 2^{m_c}, 64B/wave contiguous
        float ps[8];
#pragma unroll
        for (int j = 0; j < 8; ++j)
            ps[j] = __builtin_amdgcn_exp2f(e8[j] - m_run);   // shifted: in (0, 16]
        lacc += ((ps[0] + ps[1]) + (ps[2] + ps[3])) + ((ps[4] + ps[5]) + (ps[6] + ps[7]));
        union { f16x8 v; short4 s4[2]; } pa;
        pa.v[0] = (f16)ps[0]; pa.v[1] = (f16)ps[1]; pa.v[2] = (f16)ps[2]; pa.v[3] = (f16)ps[3];
        pa.v[4] = (f16)ps[4]; pa.v[5] = (f16)ps[5]; pa.v[6] = (f16)ps[6]; pa.v[7] = (f16)ps[7];
        // fp16 store: row L, cols [c*32+g*4, +4) and [c*32+16+g*4, +4)
        *(short4*)(arow16 + c * 64 + g * 8)      = pa.s4[0];
        *(short4*)(arow16 + c * 64 + 32 + g * 8) = pa.s4[1];
        __builtin_amdgcn_s_setprio(1);
#pragma unroll
        for (int dt = 0; dt < 12; ++dt) {
            f16x8 vf = *(const f16x8*)(Vl + (dt * 16 + L) * 80 + g * 16);
            cacc[dt] = MFMA16(pa.v, vf, cacc[dt]);
        }
        __builtin_amdgcn_s_setprio(0);
    }
    // reduce l over the 4 g-groups (each L-column holds one q-row)
    lacc += __shfl_xor(lacc, 16);
    lacc += __shfl_xor(lacc, 32);
    // lrow = 2^{-m_fin}/lacc  (absolute inverse row sum)
    if (g == 0) lrow[rowi] = __builtin_amdgcn_exp2f(-m_run) / lacc;
    float linv_r[4];
#pragma unroll
    for (int r = 0; r < 4; ++r) linv_r[r] = 1.f / __shfl(lacc, g * 4 + r);

    // ---- ctx epilogue: per-wave LDS transpose -> full-line stores ----
    __syncthreads();
    char* scr = (char*)KsB + w * 6144;                 // [16 tok][384 B]
#pragma unroll
    for (int dt = 0; dt < 12; ++dt)
#pragma unroll
        for (int r = 0; r < 4; ++r)
            *(f16*)(scr + (g * 4 + r) * 384 + (dt * 16 + L) * 2)
                = (f16)(cacc[dt][r] * linv_r[r]);
    const int b = bh >> 3, h = bh & 7;
#pragma unroll
    for (int t = 0; t < 6; ++t) {
        int chunk = t * 64 + lane;
        int tok = chunk / 24, c16 = chunk - tok * 24;
        int4 v = *(const int4*)(scr + tok * 384 + c16 * 16);
        *(int4*)((char*)ctx + ((size_t)(b * 2048 + row0 + tok) * 1536 + h * 192) * 2 + c16 * 16) = v;
    }
}

// ---------------- fused tail: proj GEMM (blocks 0..383) || fp16->fp32 normalize (384..4479) ----------------
__global__ __launch_bounds__(256) void k_tail(
    const f16* __restrict__ A, const f16* __restrict__ Bw,
    const float* __restrict__ bias, float* __restrict__ out,
    char* __restrict__ attnB, const float* __restrict__ lrow,
    const float* __restrict__ mcf)
{
    const int tid = threadIdx.x;
    if (blockIdx.x >= 384) {
        // ---- norm branch: 4096 blocks x 8 rows; in-place fp16 -> fp32 expansion ----
        const int row = (blockIdx.x - 384) * 8 + (tid >> 5);
        const int t = tid & 31;
        const float lr = lrow[row];
        char* slot = attnB + (size_t)row * 8192;
        short4 s4[16];
        float fc[16];
#pragma unroll
        for (int i = 0; i < 16; ++i) {
            s4[i] = *(const short4*)(slot + t * 8 + i * 256);          // fp16 cols t*4 + i*128
            fc[i] = mcf[(size_t)(i * 4 + (t >> 3)) * 32768 + row] * lr; // chunk (i*4 + t/8)
        }
        // wave-level drain: ALL lanes' reads complete before any fp32 write
        asm volatile("s_waitcnt vmcnt(0)" ::: "memory");
#pragma unroll
        for (int i = 0; i < 16; ++i) {
            union { short4 v; f16 h[4]; } u; u.v = s4[i];
            f32x4 o = { (float)u.h[0] * fc[i], (float)u.h[1] * fc[i],
                        (float)u.h[2] * fc[i], (float)u.h[3] * fc[i] };
            __builtin_nontemporal_store(o, (f32x4*)(slot + t * 16 + i * 512));
        }
        return;
    }
    // ---- proj branch ----
    __shared__ __align__(16) char S[32768];
    const int lane = tid & 63, w = tid >> 6;
    const int bid = blockIdx.x;
    const int xcd = bid & 7, cc = bid >> 3;
    const int mb = xcd * 4 + cc / 12, nbk = cc - (cc / 12) * 12;
    const int m0 = mb * 128, n0 = nbk * 128;
    const int wm = (w & 1) * 64, wn = (w >> 1) * 64;
    const int L = lane & 15, g = lane >> 4;
    const char* Ab = (const char*)A;
    const char* Bb = (const char*)Bw;

    const char* gA[2]; const char* gB[2]; int ldso[2];
#pragma unroll
    for (int q = 0; q < 2; ++q) {
        int s = w * 128 + q * 64 + lane;
        int swz = ((s & 3) ^ ((s >> 2) & 3)) * 16;
        gA[q] = Ab + (size_t)(m0 + (s >> 2)) * 3072 + swz;
        gB[q] = Bb + (size_t)(n0 + (s >> 2)) * 3072 + swz;
        ldso[q] = w * 2048 + q * 1024;
    }
    const int gx = ((g ^ (L & 3)) << 4);

    f32x4 acc[4][4] = {};
#pragma unroll
    for (int q = 0; q < 2; ++q) {
        gl16(gA[q], S + ldso[q]);
        gl16(gB[q], S + 8192 + ldso[q]);
    }
    int buf = 0;
    for (int kk = 0; kk < 48; ++kk) {
        __syncthreads();
        if (kk < 47) {
            int nb_ = (buf ^ 1) * 16384;
#pragma unroll
            for (int q = 0; q < 2; ++q) {
                gl16(gA[q] + (kk + 1) * 64, S + nb_ + ldso[q]);
                gl16(gB[q] + (kk + 1) * 64, S + nb_ + 8192 + ldso[q]);
            }
        }
        const char* AsB = S + buf * 16384;
        const char* BsB = AsB + 8192;
        f16x8 af[4], bf[4];
#pragma unroll
        for (int i = 0; i < 4; ++i) {
            af[i] = *(const f16x8*)(AsB + (wm + i * 16 + L) * 64 + gx);
            bf[i] = *(const f16x8*)(BsB + (wn + i * 16 + L) * 64 + gx);
        }
#pragma unroll
        for (int i = 0; i < 4; ++i)
#pragma unroll
            for (int j = 0; j < 4; ++j)
                acc[i][j] = MFMA16(bf[j], af[i], acc[i][j]);
        buf ^= 1;
    }
#pragma unroll
    for (int i = 0; i < 4; ++i) {
        int token = m0 + wm + i * 16 + L;
#pragma unroll
        for (int j = 0; j < 4; ++j) {
            int gnb = n0 + wn + j * 16 + g * 4;
            float4 bv = *(const float4*)(bias + gnb);
            float4 v = make_float4(acc[i][j][0] + bv.x, acc[i][j][1] + bv.y,
                                   acc[i][j][2] + bv.z, acc[i][j][3] + bv.w);
            *(float4*)(out + (size_t)token * 1536 + gnb) = v;
        }
    }
}

extern "C" void kernel_launch(void* const* d_in, const int* in_sizes, int n_in,
                              void* d_out, int out_size, void* d_ws, size_t ws_size,
                              hipStream_t stream)
{
    const float* x     = (const float*)d_in[0];
    const float* Wqkv  = (const float*)d_in[1];
    const float* Wproj = (const float*)d_in[2];
    const float* bproj = (const float*)d_in[3];
    const float* scale = (const float*)d_in[4];
    const float* M     = (const float*)d_in[5];
    float* out  = (float*)d_out;
    char* attnB = (char*)(out + 6291456);

    char* p = (char*)d_ws;
    f16* x_h     = (f16*)p;  p += 12582912;
    f16* Wqkv_h  = (f16*)p;  p += 14155776;
    f16* Wproj_h = (f16*)p;  p += 4718592;
    f16* Mt_h    = (f16*)p;  p += 73728;
    f16* Qh      = (f16*)p;  p += 12582912;
    f16* Kh      = (f16*)p;  p += 12582912;
    f16* Vp      = (f16*)p;  p += 12582912;
    f16* QMh     = (f16*)p;  p += 12582912;
    float* qmq   = (float*)p; p += 131072;
    float* kmk   = (float*)p; p += 131072;
    float* lrow  = (float*)p; p += 131072;
    float* mcf   = (float*)p; p += 8388608;
    f16* ctx     = (f16*)p;  p += 12582912;

    k_cvt_all<<<15504, 256, 0, stream>>>(x, Wqkv, Wproj, M, x_h, Wqkv_h, Wproj_h, Mt_h);
    k_gemm_qkv<<<1152, 256, 0, stream>>>(x_h, Wqkv_h, Qh, Kh, Vp);
    k_mgemm<<<dim3(512, 2), 256, 0, stream>>>(Qh, Kh, Mt_h, QMh, scale, qmq, kmk);
    k_attn<<<512, 256, 0, stream>>>(QMh, Kh, Vp, kmk, qmq, scale, attnB, ctx, lrow, mcf);
    k_tail<<<4480, 256, 0, stream>>>(ctx, Wproj_h, bproj, out, attnB, lrow, mcf);
    hipMemcpyAsync(out + 73400320, M, 36864 * 4, hipMemcpyDeviceToDevice, stream);
}